// Round 20
// baseline (453.773 us; speedup 1.0000x reference)
//
#include <hip/hip_runtime.h>

typedef unsigned short u16;
typedef unsigned int u32;
typedef __attribute__((ext_vector_type(8))) short short8v;
typedef __attribute__((ext_vector_type(4))) float float4v;

__device__ __forceinline__ float sigm(float x) { return 1.0f / (1.0f + __expf(-x)); }
__device__ __forceinline__ u16 f2bf(float f) {
  u32 u = __float_as_uint(f);
  u32 r = (u + 0x7fffu + ((u >> 16) & 1u)) >> 16;
  return (u16)r;
}
__device__ __forceinline__ float bf2f(u16 w) { return __uint_as_float(((u32)w) << 16); }

// ---- mega-prep: cnt zero, agg zero, pack W_e2, pack GRU weights, pack W_l1 ----
// (one dispatch; all regions elementwise/independent; packing layouts verified r9-r19)
__global__ void k_prep_all(const float* __restrict__ W2, const float* __restrict__ Wih,
                           const float* __restrict__ Whh, const float* __restrict__ Wl1,
                           u16* __restrict__ Bph, u16* __restrict__ WpI,
                           u16* __restrict__ WpH, u16* __restrict__ Wp1,
                           int* __restrict__ cnt, float* __restrict__ agg, int N) {
  long long i = (long long)blockIdx.x * blockDim.x + threadIdx.x;
  long long r0 = N;                    // cnt
  long long r1 = r0 + (long long)N * 64;  // agg
  long long r2 = r1 + 524288;          // pack_b (128*4096)
  long long r3 = r2 + 24576;           // wtf (2*12288)
  long long r4 = r3 + 12288;           // wl1
  if (i < r0) {
    cnt[i] = 0;
  } else if (i < r1) {
    agg[i - r0] = 0.0f;
  } else if (i < r2) {
    int tid = (int)(i - r1);
    int j = tid & 7;
    int lane = (tid >> 3) & 63;
    int nt = (tid >> 9) & 3;
    int ks = (tid >> 11) & 3;
    int d = tid >> 13;
    int c = lane & 15, q = lane >> 4;
    int k = ks * 32 + q * 8 + j;
    int n = d * 64 + nt * 16 + c;
    Bph[tid] = f2bf(W2[(size_t)k * 4096 + n]);
  } else if (i < r3) {
    int tid = (int)(i - r2);
    int w = tid / 12288;
    int r = tid - w * 12288;
    int jj = r & 7;
    int lane = (r >> 3) & 63;
    int t = r >> 9;
    int nt = t % 12, ks = t / 12;
    int c = lane & 15, q = lane >> 4;
    int j = nt * 16 + c;
    int k = ks * 32 + q * 8 + jj;
    const float* W = w ? Whh : Wih;
    u16* Wp = w ? WpH : WpI;
    Wp[r] = f2bf(W[j * 64 + k]);
  } else if (i < r4) {
    int tid = (int)(i - r3);
    int j = tid & 7;
    int lane = (tid >> 3) & 63;
    int nt = (tid >> 9) & 7;
    int ks = tid >> 12;
    int c = lane & 15, q = lane >> 4;
    int k = ks * 32 + q * 8 + j;
    int n = nt * 16 + c;
    Wp1[tid] = f2bf((k < 72) ? Wl1[k * 128 + n] : 0.0f);
  }
}

// ---- fused inputs: cnt atomics + node MLP + edge MLP (block-range split) ----
// cnt needs cnt zeroed -> runs after k_prep_all. Barriers only in edge blocks
// (uniform per block). node/edge math verified r5-r19.
__global__ __launch_bounds__(256) void k_inputs(
    const int* __restrict__ dst, int* __restrict__ cnt,
    const float* __restrict__ x, const float* __restrict__ Wn,
    const float* __restrict__ bn, float* __restrict__ h,
    const float* __restrict__ ea_in, const float* __restrict__ Wea,
    const float* __restrict__ bea, const float* __restrict__ We1,
    const float* __restrict__ be1, u16* __restrict__ Ahi, int N, int E) {
  int nb_cnt = (E + 255) / 256;
  int nb_node = (N * 64 + 255) / 256;
  int b = blockIdx.x;
  if (b < nb_cnt) {
    int e = b * 256 + threadIdx.x;
    if (e < E) atomicAdd(&cnt[dst[e]], 1);
    return;
  }
  b -= nb_cnt;
  if (b < nb_node) {
    int tid = b * 256 + threadIdx.x;
    if (tid < N * 64) {
      int n = tid >> 6, f = tid & 63;
      float acc = bn[f];
      for (int k = 0; k < 8; ++k) acc += x[(size_t)n * 8 + k] * Wn[k * 64 + f];
      h[tid] = fmaxf(acc, 0.0f);
    }
    return;
  }
  b -= nb_node;
  // edge MLP: 2 edges per block
  __shared__ float att[2][19];
  __shared__ float ea[2][12];
  int half = threadIdx.x >> 7;
  int t = threadIdx.x & 127;
  int e = b * 2 + half;
  bool real = (e < E);
  int ee = real ? e : E - 1;
  if (t < 19) att[half][t] = ea_in[(size_t)ee * 19 + t];
  __syncthreads();
  if (t < 12) {
    float a = bea[t];
#pragma unroll
    for (int k = 0; k < 19; ++k) a += att[half][k] * Wea[k * 12 + t];
    ea[half][t] = fmaxf(a, 0.0f);
  }
  __syncthreads();
  float a = be1[t];
#pragma unroll
  for (int j = 0; j < 12; ++j) a += ea[half][j] * We1[j * 128 + t];
  if (real) Ahi[(size_t)e * 128 + t] = f2bf(fmaxf(a, 0.0f));
}

// Fused conv   [structure verified r14/r16/r18 @87.7us: 256 thr, 2 m-tiles/wave,
// barrier-free d-loop, B reg-dbuf. This round: d-split 2->4 (16-d windows) so
// LDS 61->48KB -> 3 blocks/CU (was 2) and 1564 blocks (smaller tail) — r19
// counters showed conv ~85% stalled at Occupancy 15%.]
__global__ __launch_bounds__(256, 2) void k_conv_fused(
    const u16* __restrict__ Ahi, const u16* __restrict__ Bph,
    const float* __restrict__ b2, const float* __restrict__ h,
    const int* __restrict__ src, const int* __restrict__ dst,
    float* __restrict__ agg, int E) {
  __shared__ __align__(16) u16 sAh[128 * 136];   // 34.8 KB
  __shared__ __align__(16) float hs[128 * 20];   // 10.2 KB (16-d window)
  __shared__ __align__(16) float sb2[1024];      // 4 KB
  int m0 = blockIdx.x * 128;
  int d0 = blockIdx.y * 16;
  int tid = threadIdx.x;
#pragma unroll
  for (int p = 0; p < 8; ++p) {
    int slot = p * 256 + tid;
    int r = slot >> 4, s = slot & 15;
    int gr = m0 + r;
    if (gr >= E) gr = E - 1;
    *(uint4*)(&sAh[r * 136 + s * 8]) = *(const uint4*)(Ahi + (size_t)gr * 128 + s * 8);
  }
#pragma unroll
  for (int p = 0; p < 2; ++p) {
    int slot = p * 256 + tid;        // 512 slots = 128 rows x 4 float4 (16 d-vals)
    int r = slot >> 2, s = slot & 3;
    int ge = m0 + r;
    if (ge >= E) ge = E - 1;
    int sn = src[ge];
    *(float4*)(&hs[r * 20 + s * 4]) = *(const float4*)(h + (size_t)sn * 64 + d0 + s * 4);
  }
  {
    int slot = tid;                  // 256 float4 = 1024 floats of b2 slice
    *(float4*)(&sb2[slot * 4]) = *(const float4*)(b2 + d0 * 64 + slot * 4);
  }
  __syncthreads();
  int wave = tid >> 6, lane = tid & 63;
  int c = lane & 15, q = lane >> 4;
  float msg[2][4][4];
#pragma unroll
  for (int mt = 0; mt < 2; ++mt)
#pragma unroll
    for (int nt = 0; nt < 4; ++nt)
#pragma unroll
      for (int r = 0; r < 4; ++r) msg[mt][nt][r] = 0.0f;

  short8v bufA[16], bufB[16];
  auto loadB = [&](int dd, short8v* buf) {
    const u16* bp = Bph + (size_t)dd * 8192 + lane * 8;
#pragma unroll
    for (int i = 0; i < 16; ++i) buf[i] = *(const short8v*)(bp + i * 512);
  };
  auto compute = [&](int dd, const short8v* buf) {
    int dl = dd - d0;
#pragma unroll
    for (int mt = 0; mt < 2; ++mt) {
      int arow = wave * 32 + mt * 16 + c;
      float4v acc[4];
#pragma unroll
      for (int nt = 0; nt < 4; ++nt) acc[nt] = (float4v){0.f, 0.f, 0.f, 0.f};
#pragma unroll
      for (int ks = 0; ks < 4; ++ks) {
        short8v ah = *(const short8v*)(&sAh[arow * 136 + ks * 32 + q * 8]);
#pragma unroll
        for (int nt = 0; nt < 4; ++nt)
          acc[nt] = __builtin_amdgcn_mfma_f32_16x16x32_bf16(ah, buf[ks * 4 + nt], acc[nt], 0, 0, 0);
      }
      float hd[4];
#pragma unroll
      for (int r = 0; r < 4; ++r)
        hd[r] = hs[(wave * 32 + mt * 16 + q * 4 + r) * 20 + dl];
#pragma unroll
      for (int nt = 0; nt < 4; ++nt) {
        float b2v = sb2[dl * 64 + nt * 16 + c];
#pragma unroll
        for (int r = 0; r < 4; ++r) msg[mt][nt][r] += hd[r] * (acc[nt][r] + b2v);
      }
    }
  };

  loadB(d0, bufA);
  for (int d = d0; d < d0 + 16; d += 2) {
    loadB(d + 1, bufB);
    compute(d, bufA);
    if (d + 2 < d0 + 16) loadB(d + 2, bufA);
    compute(d + 1, bufB);
  }
#pragma unroll
  for (int mt = 0; mt < 2; ++mt) {
#pragma unroll
    for (int r = 0; r < 4; ++r) {
      int e = m0 + wave * 32 + mt * 16 + q * 4 + r;
      if (e < E) {
        int dn = dst[e];
        float* ap = agg + (size_t)dn * 64 + c;
#pragma unroll
        for (int nt = 0; nt < 4; ++nt) atomicAdd(ap + nt * 16, msg[mt][nt][r]);
      }
    }
  }
}

// MFMA GRU   [verified r16-r19]
__global__ __launch_bounds__(256, 2) void k_gru_mfma(
    float* __restrict__ agg, const int* __restrict__ cnt,
    const float* __restrict__ cb, const u16* __restrict__ WpI,
    const u16* __restrict__ WpH, const float* __restrict__ bih,
    const float* __restrict__ bhh, const float* __restrict__ hin,
    float* __restrict__ hout, int N) {
  __shared__ __align__(16) u16 sM[64 * 72];
  __shared__ __align__(16) u16 sH[64 * 72];
  __shared__ __align__(16) float sHf[64 * 68];
  int n0 = blockIdx.x * 64;
  int tid = threadIdx.x;
#pragma unroll
  for (int p = 0; p < 16; ++p) {
    int slot = p * 256 + tid;
    int n = slot >> 6, f = slot & 63;
    int gn = n0 + n;
    bool real = (gn < N);
    if (!real) gn = N - 1;
    float cf = fmaxf((float)cnt[gn], 1.0f);
    float av = agg[(size_t)gn * 64 + f];
    if (real) agg[(size_t)gn * 64 + f] = 0.0f;
    float m = fmaxf(av / cf + cb[f], 0.0f);
    float hv = hin[(size_t)gn * 64 + f];
    sM[n * 72 + f] = f2bf(m);
    sH[n * 72 + f] = f2bf(hv);
    sHf[n * 68 + f] = hv;
  }
  __syncthreads();
  int wave = tid >> 6, lane = tid & 63;
  int c = lane & 15, q = lane >> 4;
  short8v am[2], ah[2];
#pragma unroll
  for (int ks = 0; ks < 2; ++ks) {
    am[ks] = *(const short8v*)(&sM[(wave * 16 + c) * 72 + ks * 32 + q * 8]);
    ah[ks] = *(const short8v*)(&sH[(wave * 16 + c) * 72 + ks * 32 + q * 8]);
  }
  float4v accRZ[8], accN[4], accHN[4];
#pragma unroll
  for (int i = 0; i < 8; ++i) accRZ[i] = (float4v){0.f, 0.f, 0.f, 0.f};
#pragma unroll
  for (int i = 0; i < 4; ++i) {
    accN[i] = (float4v){0.f, 0.f, 0.f, 0.f};
    accHN[i] = (float4v){0.f, 0.f, 0.f, 0.f};
  }
#pragma unroll
  for (int ks = 0; ks < 2; ++ks) {
#pragma unroll
    for (int nt = 0; nt < 8; ++nt) {
      short8v bI = *(const short8v*)(WpI + ((size_t)(ks * 12 + nt) * 64 + lane) * 8);
      short8v bH = *(const short8v*)(WpH + ((size_t)(ks * 12 + nt) * 64 + lane) * 8);
      accRZ[nt] = __builtin_amdgcn_mfma_f32_16x16x32_bf16(am[ks], bI, accRZ[nt], 0, 0, 0);
      accRZ[nt] = __builtin_amdgcn_mfma_f32_16x16x32_bf16(ah[ks], bH, accRZ[nt], 0, 0, 0);
    }
#pragma unroll
    for (int nt = 0; nt < 4; ++nt) {
      short8v bI = *(const short8v*)(WpI + ((size_t)(ks * 12 + 8 + nt) * 64 + lane) * 8);
      short8v bH = *(const short8v*)(WpH + ((size_t)(ks * 12 + 8 + nt) * 64 + lane) * 8);
      accN[nt] = __builtin_amdgcn_mfma_f32_16x16x32_bf16(am[ks], bI, accN[nt], 0, 0, 0);
      accHN[nt] = __builtin_amdgcn_mfma_f32_16x16x32_bf16(ah[ks], bH, accHN[nt], 0, 0, 0);
    }
  }
#pragma unroll
  for (int nt = 0; nt < 4; ++nt) {
    int f = nt * 16 + c;
    float brz_r = bih[f] + bhh[f];
    float brz_z = bih[64 + f] + bhh[64 + f];
    float bin = bih[128 + f];
    float bhn = bhh[128 + f];
#pragma unroll
    for (int r = 0; r < 4; ++r) {
      int nl = wave * 16 + q * 4 + r;
      int gn = n0 + nl;
      float rr = sigm(accRZ[nt][r] + brz_r);
      float zz = sigm(accRZ[nt + 4][r] + brz_z);
      float ng = tanhf(accN[nt][r] + bin + rr * (accHN[nt][r] + bhn));
      float hv = sHf[nl * 68 + f];
      if (gn < N) hout[(size_t)gn * 64 + f] = (1.0f - zz) * ng + zz * hv;
    }
  }
}

// MFMA final MLP   [verified r19; staging now lane=feature coalesced]
__global__ __launch_bounds__(256) void k_final_mfma(
    const float* __restrict__ h, const float* __restrict__ ea3,
    const int* __restrict__ idx3, const u16* __restrict__ Wp1,
    const float* __restrict__ bl1, const float* __restrict__ Wl2,
    const float* __restrict__ bl2, float* __restrict__ out, int E3) {
  __shared__ __align__(16) u16 sF[64 * 104];
  int e0 = blockIdx.x * 64;
  int tid = threadIdx.x;
#pragma unroll
  for (int p = 0; p < 16; ++p) {
    int er = p * 4 + (tid >> 6);
    int kk = tid & 63;
    int ge = e0 + er;
    int gc = (ge < E3) ? ge : E3 - 1;
    int a = idx3[gc], b = idx3[E3 + gc];
    sF[er * 104 + kk] = f2bf(0.5f * (h[(size_t)a * 64 + kk] + h[(size_t)b * 64 + kk]));
  }
#pragma unroll
  for (int p = 0; p < 8; ++p) {
    int slot = p * 256 + tid;        // 2048 = 64 edges x 32 (kk 64..95)
    int er = slot >> 5;
    int kk = 64 + (slot & 31);
    int ge = e0 + er;
    int gc = (ge < E3) ? ge : E3 - 1;
    float v = (kk < 72) ? ea3[(size_t)gc * 8 + (kk - 64)] : 0.0f;
    sF[er * 104 + kk] = f2bf(v);
  }
  __syncthreads();
  int wave = tid >> 6, lane = tid & 63;
  int c = lane & 15, q = lane >> 4;
  float4v acc[8];
#pragma unroll
  for (int nt = 0; nt < 8; ++nt) acc[nt] = (float4v){0.f, 0.f, 0.f, 0.f};
#pragma unroll
  for (int ks = 0; ks < 3; ++ks) {
    short8v af = *(const short8v*)(&sF[(wave * 16 + c) * 104 + ks * 32 + q * 8]);
#pragma unroll
    for (int nt = 0; nt < 8; ++nt) {
      short8v bf = *(const short8v*)(Wp1 + ((size_t)(ks * 8 + nt) * 64 + lane) * 8);
      acc[nt] = __builtin_amdgcn_mfma_f32_16x16x32_bf16(af, bf, acc[nt], 0, 0, 0);
    }
  }
  float v[4] = {0.f, 0.f, 0.f, 0.f};
#pragma unroll
  for (int nt = 0; nt < 8; ++nt) {
    int n = nt * 16 + c;
    float b1 = bl1[n];
    float w2 = Wl2[n];
#pragma unroll
    for (int r = 0; r < 4; ++r) v[r] += fmaxf(acc[nt][r] + b1, 0.0f) * w2;
  }
#pragma unroll
  for (int off = 1; off < 16; off <<= 1) {
#pragma unroll
    for (int r = 0; r < 4; ++r) v[r] += __shfl_xor(v[r], off);
  }
  if (c == 0) {
    float b2v = bl2[0];
#pragma unroll
    for (int r = 0; r < 4; ++r) {
      int e = e0 + wave * 16 + q * 4 + r;
      if (e < E3) out[e] = v[r] + b2v;
    }
  }
}

extern "C" void kernel_launch(void* const* d_in, const int* in_sizes, int n_in,
                              void* d_out, int out_size, void* d_ws, size_t ws_size,
                              hipStream_t stream) {
  const float* x          = (const float*)d_in[0];
  const float* edge_attr  = (const float*)d_in[1];
  const float* edge_attr3 = (const float*)d_in[2];
  const int*   edge_index = (const int*)d_in[3];
  const int*   edge_index3= (const int*)d_in[4];
  const float* W_node = (const float*)d_in[5];
  const float* b_node = (const float*)d_in[6];
  const float* W_ea   = (const float*)d_in[7];
  const float* b_ea   = (const float*)d_in[8];
  const float* W_e1   = (const float*)d_in[9];
  const float* b_e1   = (const float*)d_in[10];
  const float* W_e2   = (const float*)d_in[11];
  const float* b_e2   = (const float*)d_in[12];
  const float* conv_bias = (const float*)d_in[13];
  const float* W_ih   = (const float*)d_in[14];
  const float* b_ih   = (const float*)d_in[15];
  const float* W_hh   = (const float*)d_in[16];
  const float* b_hh   = (const float*)d_in[17];
  const float* W_l1   = (const float*)d_in[18];
  const float* b_l1   = (const float*)d_in[19];
  const float* W_l2   = (const float*)d_in[20];
  const float* b_l2   = (const float*)d_in[21];

  int N  = in_sizes[0] / 8;
  int E  = in_sizes[1] / 19;
  int E3 = in_sizes[2] / 8;

  char* p = (char*)d_ws;
  auto carve = [&](size_t bytes) -> void* {
    char* q = p;
    p += (bytes + 255) & ~(size_t)255;
    return (void*)q;
  };
  float* hA   = (float*)carve((size_t)N * 64 * 4);
  float* hB   = (float*)carve((size_t)N * 64 * 4);
  float* agg  = (float*)carve((size_t)N * 64 * 4);
  int*   cnt  = (int*)carve((size_t)N * 4);
  u16*   Ahi  = (u16*)carve((size_t)E * 128 * 2);
  u16*   Bph  = (u16*)carve((size_t)128 * 4096 * 2);
  u16*   WpI  = (u16*)carve(12288 * 2);
  u16*   WpH  = (u16*)carve(12288 * 2);
  u16*   Wp1  = (u16*)carve(12288 * 2);

  const int* src = edge_index;
  const int* dst = edge_index + E;

  long long prep_tot = (long long)N + (long long)N * 64 + 524288 + 24576 + 12288;
  k_prep_all<<<(unsigned)((prep_tot + 255) / 256), 256, 0, stream>>>(
      W_e2, W_ih, W_hh, W_l1, Bph, WpI, WpH, Wp1, cnt, agg, N);
  int nb_cnt = (E + 255) / 256;
  int nb_node = (N * 64 + 255) / 256;
  int nb_edge = (E + 1) / 2;
  k_inputs<<<nb_cnt + nb_node + nb_edge, 256, 0, stream>>>(
      dst, cnt, x, W_node, b_node, hA, edge_attr, W_ea, b_ea, W_e1, b_e1, Ahi, N, E);

  float* hcur = hA;
  float* hnxt = hB;
  dim3 gconv((E + 127) / 128, 4);
  int ngru = (N + 63) / 64;
  for (int it = 0; it < 3; ++it) {
    k_conv_fused<<<gconv, 256, 0, stream>>>(Ahi, Bph, b_e2, hcur, src, dst, agg, E);
    k_gru_mfma<<<ngru, 256, 0, stream>>>(agg, cnt, conv_bias, WpI, WpH,
                                         b_ih, b_hh, hcur, hnxt, N);
    float* tmp = hcur; hcur = hnxt; hnxt = tmp;
  }
  k_final_mfma<<<(E3 + 63) / 64, 256, 0, stream>>>(hcur, edge_attr3, edge_index3, Wp1,
                                                   b_l1, W_l2, b_l2, (float*)d_out, E3);
}